// Round 11
// baseline (199.186 us; speedup 1.0000x reference)
//
#include <hip/hip_runtime.h>
#include <stdint.h>

namespace {
constexpr int kH = 16;
constexpr int kS = 8192;
constexpr int kD = 64;
constexpr int kW = 1024;

typedef __attribute__((ext_vector_type(4)))  float float4_t;
typedef __attribute__((ext_vector_type(16))) float f32x16;
typedef __attribute__((ext_vector_type(8)))  short bf16x8;
typedef __attribute__((ext_vector_type(8)))  short short8_t;

__device__ __forceinline__ unsigned short f2bf(float f) {
    union { float fv; uint32_t u; } c; c.fv = f;
    return (unsigned short)((c.u + 0x7fffu + ((c.u >> 16) & 1u)) >> 16);
}

__device__ __forceinline__ float fexp2(float x) {
#if __has_builtin(__builtin_amdgcn_exp2f)
    return __builtin_amdgcn_exp2f(x);
#else
    return exp2f(x);
#endif
}

__device__ __forceinline__ void gload16(const void* g, char* l) {
    __builtin_amdgcn_global_load_lds(
        (const __attribute__((address_space(1))) void*)g,
        (__attribute__((address_space(3))) void*)l, 16, 0, 0);
}

// ---- fused prepass: K fp32->bf16 + V transpose (64 seq rows per block) ----
__global__ __launch_bounds__(256)
void prep_kv(const float* __restrict__ K, const float* __restrict__ V,
             unsigned short* __restrict__ Kb, unsigned short* __restrict__ Vt) {
    __shared__ float tile[64][65];
    const int h  = blockIdx.y;
    const int s0 = blockIdx.x * 64;
    const int tid = threadIdx.x;
    const size_t hb = (size_t)h * kS * kD;

    // K convert: 64x64 elems, 16 per thread
    {
        const size_t base = hb + (size_t)s0 * kD + (size_t)tid * 16;
        float4_t a = *(const float4_t*)(K + base);
        float4_t b = *(const float4_t*)(K + base + 4);
        float4_t c = *(const float4_t*)(K + base + 8);
        float4_t d = *(const float4_t*)(K + base + 12);
        short8_t o0, o1;
        #pragma unroll
        for (int j = 0; j < 4; ++j) {
            o0[j] = (short)f2bf(a[j]); o0[j + 4] = (short)f2bf(b[j]);
            o1[j] = (short)f2bf(c[j]); o1[j + 4] = (short)f2bf(d[j]);
        }
        *(short8_t*)(Kb + base)     = o0;
        *(short8_t*)(Kb + base + 8) = o1;
    }

    // V transpose -> Vt [D][S]
    #pragma unroll
    for (int it = 0; it < 4; ++it) {
        const int n = tid + it * 256;
        const int s = n >> 4, d0 = (n & 15) * 4;
        float4_t v = *(const float4_t*)(V + hb + (size_t)(s0 + s) * kD + d0);
        tile[s][d0 + 0] = v[0]; tile[s][d0 + 1] = v[1];
        tile[s][d0 + 2] = v[2]; tile[s][d0 + 3] = v[3];
    }
    __syncthreads();
    #pragma unroll
    for (int it = 0; it < 2; ++it) {
        const int n = tid + it * 256;
        const int d = n >> 3, sc = (n & 7) * 8;
        short8_t o;
        #pragma unroll
        for (int j = 0; j < 8; ++j) o[j] = (short)f2bf(tile[sc + j][d]);
        *(short8_t*)(Vt + (size_t)h * kD * kS + (size_t)d * kS + s0 + sc) = o;
    }
}

// ---- main: 32 q/wave, 128 q/block, 2-buffer LDS, 5 blocks/CU ----
__global__ __launch_bounds__(256, 5)
void swa_main(const float* __restrict__ Qg, const unsigned short* __restrict__ Kb,
              const unsigned short* __restrict__ Vt, float* __restrict__ Og) {
    // per buffer: [0,8K) K tile [64 keys][128B], [8K,16K) V^T tile [64 d][128B]
    __shared__ __align__(16) char lds[2][16384];

    const int lid  = blockIdx.x;                      // 0..1023
    const int swz  = (lid & 7) * 128 + (lid >> 3);    // XCD-chunked, bijective
    const int h    = swz >> 6;
    const int qblk = swz & 63;

    const int tid  = threadIdx.x;
    const int wv   = tid >> 6;
    const int lane = tid & 63;
    const int lq   = lane & 31;
    const int hi   = lane >> 5;

    const int q0b = qblk * 128;
    const int qs  = q0b + wv * 32;
    const int q   = qs + lq;
    const size_t hb  = (size_t)h * kS * kD;
    const size_t hbv = (size_t)h * kD * kS;

    // ---- Q B-fragment; scale folded with log2(e) ----
    constexpr float qscale = 0.125f * 1.44269504f;
    bf16x8 qf[4];
    {
        const float* qp = Qg + hb + (size_t)q * kD + hi * 8;
        #pragma unroll
        for (int c = 0; c < 4; ++c) {
            float4_t a = *(const float4_t*)(qp + c * 16);
            float4_t b = *(const float4_t*)(qp + c * 16 + 4);
            bf16x8 f;
            #pragma unroll
            for (int j = 0; j < 4; ++j) {
                f[j]     = (short)f2bf(a[j] * qscale);
                f[j + 4] = (short)f2bf(b[j] * qscale);
            }
            qf[c] = f;
        }
    }

    f32x16 acc[2], lsum;
    #pragma unroll
    for (int r = 0; r < 16; ++r) { acc[0][r] = 0.f; acc[1][r] = 0.f; lsum[r] = 0.f; }

    bf16x8 ones;
    #pragma unroll
    for (int j = 0; j < 8; ++j) ones[j] = (short)0x3F80;   // bf16 1.0

    const int kstart = (q0b >= kW) ? q0b - kW : 0;
    const int nt     = (q0b + 128 - kstart) >> 6;

    // staging: dest chunk n = tid + i*256 (linear); src chunk c = n ^ ((n>>3)&7)
    int srcK[2], srcV[2];
    #pragma unroll
    for (int i = 0; i < 2; ++i) {
        const int n = tid + i * 256;
        const int c = n ^ ((n >> 3) & 7);
        srcK[i] = (c >> 3) * 64 + (c & 7) * 8;
        srcV[i] = (c >> 3) * kS + (c & 7) * 8;
    }
    const unsigned short* KbH = Kb + hb;
    const unsigned short* VtH = Vt + hbv;

    auto stage = [&](int buf, int kb) {
        const unsigned short* Kt = KbH + (size_t)kb * 64;
        const unsigned short* Vq = VtH + kb;
        #pragma unroll
        for (int i = 0; i < 2; ++i) {
            const int db = i * 4096 + wv * 1024;
            gload16(Kt + srcK[i], &lds[buf][db]);
            gload16(Vq + srcV[i], &lds[buf][8192 + db]);
        }
    };

    stage(0, kstart);
    for (int t = 0; t < nt; ++t) {
        const int kb  = kstart + t * 64;
        const int kbn = (t + 1 < nt) ? kb + 64 : kb;
        stage((t + 1) & 1, kbn);                         // prefetch next tile
        asm volatile("s_waitcnt vmcnt(4)" ::: "memory"); // tile t staged; 4 newest in flight
        __builtin_amdgcn_s_barrier();
        asm volatile("" ::: "memory");

        const char* Kl = lds[t & 1];
        const char* Vl = lds[t & 1] + 8192;

        #pragma unroll
        for (int half = 0; half < 2; ++half) {
            const int kh = kb + half * 32;
            if (kh <= qs && kh >= qs - kW) {             // wave-uniform active check
                // K A-frags
                const int krow = half * 32 + lq;
                const int ksw  = (lq & 7) << 4;          // krow&7 == lq&7
                bf16x8 kf[4];
                #pragma unroll
                for (int c = 0; c < 4; ++c)
                    kf[c] = *(const bf16x8*)(Kl + ((krow * 128 + c * 32 + hi * 16) ^ ksw));

                f32x16 st;
                #pragma unroll
                for (int r = 0; r < 16; ++r) st[r] = 0.f;
                __builtin_amdgcn_s_setprio(1);
                #pragma unroll
                for (int c = 0; c < 4; ++c)
                    st = __builtin_amdgcn_mfma_f32_32x32x16_bf16(kf[c], qf[c], st, 0, 0, 0);
                __builtin_amdgcn_s_setprio(0);

                // V A-frags (issue early; latency hides under softmax)
                bf16x8 vf[4];
                #pragma unroll
                for (int dh = 0; dh < 2; ++dh)
                    #pragma unroll
                    for (int kc = 0; kc < 2; ++kc)
                        vf[dh * 2 + kc] = *(const bf16x8*)(
                            Vl + (((dh * 32 + lq) * 128 + half * 64 + kc * 32 + hi * 16) ^ ksw));

                // max-free softmax numerators (exp2 domain)
                float p[16];
                const bool interior = (kh <= qs - 32) && (kh >= qs - 992);
                if (interior) {
                    #pragma unroll
                    for (int r = 0; r < 16; ++r) p[r] = fexp2(st[r]);
                } else {
                    #pragma unroll
                    for (int r = 0; r < 16; ++r) {
                        const int ki = kh + (r & 3) + 8 * (r >> 2) + 4 * hi;
                        const bool ok = (ki <= q) && (ki + kW >= q);
                        const float e = fexp2(st[r]);
                        p[r] = ok ? e : 0.f;
                    }
                }

                // P^T -> bf16 B-frags (verified cvt_pk + permlane order)
                unsigned int wrd[8];
                #pragma unroll
                for (int j = 0; j < 8; ++j)
                    asm("v_cvt_pk_bf16_f32 %0, %1, %2" : "=v"(wrd[j]) : "v"(p[2 * j]), "v"(p[2 * j + 1]));
                asm("v_permlane32_swap_b32 %0, %1" : "+v"(wrd[0]), "+v"(wrd[2]));
                asm("v_permlane32_swap_b32 %0, %1" : "+v"(wrd[1]), "+v"(wrd[3]));
                asm("v_permlane32_swap_b32 %0, %1" : "+v"(wrd[4]), "+v"(wrd[6]));
                asm("v_permlane32_swap_b32 %0, %1" : "+v"(wrd[5]), "+v"(wrd[7]));
                union U { unsigned int u[4]; bf16x8 v; };
                U u0, u1;
                u0.u[0] = wrd[0]; u0.u[1] = wrd[1]; u0.u[2] = wrd[2]; u0.u[3] = wrd[3];
                u1.u[0] = wrd[4]; u1.u[1] = wrd[5]; u1.u[2] = wrd[6]; u1.u[3] = wrd[7];

                __builtin_amdgcn_s_setprio(1);
                acc[0] = __builtin_amdgcn_mfma_f32_32x32x16_bf16(vf[0], u0.v, acc[0], 0, 0, 0);
                acc[1] = __builtin_amdgcn_mfma_f32_32x32x16_bf16(vf[2], u0.v, acc[1], 0, 0, 0);
                lsum   = __builtin_amdgcn_mfma_f32_32x32x16_bf16(ones,  u0.v, lsum,   0, 0, 0);
                acc[0] = __builtin_amdgcn_mfma_f32_32x32x16_bf16(vf[1], u1.v, acc[0], 0, 0, 0);
                acc[1] = __builtin_amdgcn_mfma_f32_32x32x16_bf16(vf[3], u1.v, acc[1], 0, 0, 0);
                lsum   = __builtin_amdgcn_mfma_f32_32x32x16_bf16(ones,  u1.v, lsum,   0, 0, 0);
                __builtin_amdgcn_s_setprio(0);
            }
        }

        asm volatile("" ::: "memory");
        __builtin_amdgcn_s_barrier();                   // buf fully read before rewrite
        asm volatile("" ::: "memory");
    }

    // ---- epilogue: denominator from lsum (all regs = row sum), store ----
    const float rl = 1.f / lsum[0];
    float* op = Og + hb + (size_t)q * kD;
    #pragma unroll
    for (int g = 0; g < 4; ++g) {
        float4_t o0, o1;
        #pragma unroll
        for (int j = 0; j < 4; ++j) {
            o0[j] = acc[0][g * 4 + j] * rl;
            o1[j] = acc[1][g * 4 + j] * rl;
        }
        *(float4_t*)(op + g * 8 + hi * 4)      = o0;
        *(float4_t*)(op + 32 + g * 8 + hi * 4) = o1;
    }
}
} // namespace

extern "C" void kernel_launch(void* const* d_in, const int* in_sizes, int n_in,
                              void* d_out, int out_size, void* d_ws, size_t ws_size,
                              hipStream_t stream) {
    (void)in_sizes; (void)n_in; (void)out_size; (void)ws_size;
    const float* Q = (const float*)d_in[0];
    const float* K = (const float*)d_in[1];
    const float* V = (const float*)d_in[2];
    float* O = (float*)d_out;
    unsigned short* Kb = (unsigned short*)d_ws;
    unsigned short* Vt = Kb + (size_t)kH * kS * kD;

    prep_kv<<<dim3(kS / 64, kH), dim3(256), 0, stream>>>(K, V, Kb, Vt);
    swa_main<<<dim3(1024), dim3(256), 0, stream>>>(Q, Kb, Vt, O);
}

// Round 12
// 79.275 us; speedup vs baseline: 2.5126x; 2.5126x over previous
//
#include <hip/hip_runtime.h>
#include <stdint.h>

namespace {
constexpr int kH = 16;
constexpr int kS = 8192;
constexpr int kD = 64;
constexpr int kW = 1024;

typedef __attribute__((ext_vector_type(4)))  float float4_t;
typedef __attribute__((ext_vector_type(16))) float f32x16;
typedef __attribute__((ext_vector_type(8)))  short bf16x8;
typedef __attribute__((ext_vector_type(8)))  short short8_t;

__device__ __forceinline__ unsigned short f2bf(float f) {
    union { float fv; uint32_t u; } c; c.fv = f;
    return (unsigned short)((c.u + 0x7fffu + ((c.u >> 16) & 1u)) >> 16);
}

__device__ __forceinline__ float fexp2(float x) {
#if __has_builtin(__builtin_amdgcn_exp2f)
    return __builtin_amdgcn_exp2f(x);
#else
    return exp2f(x);
#endif
}

__device__ __forceinline__ void gload16(const void* g, char* l) {
    __builtin_amdgcn_global_load_lds(
        (const __attribute__((address_space(1))) void*)g,
        (__attribute__((address_space(3))) void*)l, 16, 0, 0);
}

// ---- fused prepass: K fp32->bf16 + V transpose (64 seq rows per block) ----
__global__ __launch_bounds__(256)
void prep_kv(const float* __restrict__ K, const float* __restrict__ V,
             unsigned short* __restrict__ Kb, unsigned short* __restrict__ Vt) {
    __shared__ float tile[64][65];
    const int h  = blockIdx.y;
    const int s0 = blockIdx.x * 64;
    const int tid = threadIdx.x;
    const size_t hb = (size_t)h * kS * kD;

    // K convert: 64x64 elems, 16 per thread
    {
        const size_t base = hb + (size_t)s0 * kD + (size_t)tid * 16;
        float4_t a = *(const float4_t*)(K + base);
        float4_t b = *(const float4_t*)(K + base + 4);
        float4_t c = *(const float4_t*)(K + base + 8);
        float4_t d = *(const float4_t*)(K + base + 12);
        short8_t o0, o1;
        #pragma unroll
        for (int j = 0; j < 4; ++j) {
            o0[j] = (short)f2bf(a[j]); o0[j + 4] = (short)f2bf(b[j]);
            o1[j] = (short)f2bf(c[j]); o1[j + 4] = (short)f2bf(d[j]);
        }
        *(short8_t*)(Kb + base)     = o0;
        *(short8_t*)(Kb + base + 8) = o1;
    }

    // V transpose -> Vt [D][S]
    #pragma unroll
    for (int it = 0; it < 4; ++it) {
        const int n = tid + it * 256;
        const int s = n >> 4, d0 = (n & 15) * 4;
        float4_t v = *(const float4_t*)(V + hb + (size_t)(s0 + s) * kD + d0);
        tile[s][d0 + 0] = v[0]; tile[s][d0 + 1] = v[1];
        tile[s][d0 + 2] = v[2]; tile[s][d0 + 3] = v[3];
    }
    __syncthreads();
    #pragma unroll
    for (int it = 0; it < 2; ++it) {
        const int n = tid + it * 256;
        const int d = n >> 3, sc = (n & 7) * 8;
        short8_t o;
        #pragma unroll
        for (int j = 0; j < 8; ++j) o[j] = (short)f2bf(tile[sc + j][d]);
        *(short8_t*)(Vt + (size_t)h * kD * kS + (size_t)d * kS + s0 + sc) = o;
    }
}

// ---- main: R6 skeleton (2-buf, vmcnt(4), 2 barriers, 4 blk/CU) + lsum-MFMA ----
__global__ __launch_bounds__(256, 4)
void swa_main(const float* __restrict__ Qg, const unsigned short* __restrict__ Kb,
              const unsigned short* __restrict__ Vt, float* __restrict__ Og) {
    // per buffer: [0,8K) K tile [64 keys][128B], [8K,16K) V^T tile [64 d][128B]
    __shared__ __align__(16) char lds[2][16384];

    const int lid  = blockIdx.x;                      // 0..1023
    const int swz  = (lid & 7) * 128 + (lid >> 3);    // XCD-chunked, bijective
    const int h    = swz >> 6;
    const int qblk = swz & 63;

    const int tid  = threadIdx.x;
    const int wv   = tid >> 6;
    const int lane = tid & 63;
    const int lq   = lane & 31;
    const int hi   = lane >> 5;

    const int q0b = qblk * 128;
    const int qs  = q0b + wv * 32;
    const int q   = qs + lq;
    const size_t hb  = (size_t)h * kS * kD;
    const size_t hbv = (size_t)h * kD * kS;

    // ---- Q B-fragment; scale folded with log2(e) ----
    constexpr float qscale = 0.125f * 1.44269504f;
    bf16x8 qf[4];
    {
        const float* qp = Qg + hb + (size_t)q * kD + hi * 8;
        #pragma unroll
        for (int c = 0; c < 4; ++c) {
            float4_t a = *(const float4_t*)(qp + c * 16);
            float4_t b = *(const float4_t*)(qp + c * 16 + 4);
            bf16x8 f;
            #pragma unroll
            for (int j = 0; j < 4; ++j) {
                f[j]     = (short)f2bf(a[j] * qscale);
                f[j + 4] = (short)f2bf(b[j] * qscale);
            }
            qf[c] = f;
        }
    }

    f32x16 acc[2], lsum;
    #pragma unroll
    for (int r = 0; r < 16; ++r) { acc[0][r] = 0.f; acc[1][r] = 0.f; lsum[r] = 0.f; }

    bf16x8 ones;
    #pragma unroll
    for (int j = 0; j < 8; ++j) ones[j] = (short)0x3F80;   // bf16 1.0

    const int kstart = (q0b >= kW) ? q0b - kW : 0;
    const int nt     = (q0b + 128 - kstart) >> 6;

    // staging: dest chunk n = tid + i*256 (linear); src chunk c = n ^ ((n>>3)&7)
    int srcK[2], srcV[2];
    #pragma unroll
    for (int i = 0; i < 2; ++i) {
        const int n = tid + i * 256;
        const int c = n ^ ((n >> 3) & 7);
        srcK[i] = (c >> 3) * 64 + (c & 7) * 8;
        srcV[i] = (c >> 3) * kS + (c & 7) * 8;
    }
    const unsigned short* KbH = Kb + hb;
    const unsigned short* VtH = Vt + hbv;

    auto stage = [&](int buf, int kb) {
        const unsigned short* Kt = KbH + (size_t)kb * 64;
        const unsigned short* Vq = VtH + kb;
        #pragma unroll
        for (int i = 0; i < 2; ++i) {
            const int db = i * 4096 + wv * 1024;
            gload16(Kt + srcK[i], &lds[buf][db]);
            gload16(Vq + srcV[i], &lds[buf][8192 + db]);
        }
    };

    stage(0, kstart);
    for (int t = 0; t < nt; ++t) {
        const int kb  = kstart + t * 64;
        const int kbn = (t + 1 < nt) ? kb + 64 : kb;
        stage((t + 1) & 1, kbn);                         // prefetch next tile
        asm volatile("s_waitcnt vmcnt(4)" ::: "memory"); // tile t staged; 4 newest in flight
        __builtin_amdgcn_s_barrier();
        asm volatile("" ::: "memory");

        const char* Kl = lds[t & 1];
        const char* Vl = lds[t & 1] + 8192;

        #pragma unroll
        for (int half = 0; half < 2; ++half) {
            const int kh = kb + half * 32;
            if (kh <= qs && kh >= qs - kW) {             // wave-uniform active check
                // K A-frags
                const int krow = half * 32 + lq;
                const int ksw  = (lq & 7) << 4;          // krow&7 == lq&7
                bf16x8 kf[4];
                #pragma unroll
                for (int c = 0; c < 4; ++c)
                    kf[c] = *(const bf16x8*)(Kl + ((krow * 128 + c * 32 + hi * 16) ^ ksw));

                f32x16 st;
                #pragma unroll
                for (int r = 0; r < 16; ++r) st[r] = 0.f;
                __builtin_amdgcn_s_setprio(1);
                #pragma unroll
                for (int c = 0; c < 4; ++c)
                    st = __builtin_amdgcn_mfma_f32_32x32x16_bf16(kf[c], qf[c], st, 0, 0, 0);
                __builtin_amdgcn_s_setprio(0);

                // V A-frags (issue early; latency hides under softmax)
                bf16x8 vf[4];
                #pragma unroll
                for (int dh = 0; dh < 2; ++dh)
                    #pragma unroll
                    for (int kc = 0; kc < 2; ++kc)
                        vf[dh * 2 + kc] = *(const bf16x8*)(
                            Vl + (((dh * 32 + lq) * 128 + half * 64 + kc * 32 + hi * 16) ^ ksw));

                // max-free softmax numerators (exp2 domain)
                float p[16];
                const bool interior = (kh <= qs - 32) && (kh >= qs - 992);
                if (interior) {
                    #pragma unroll
                    for (int r = 0; r < 16; ++r) p[r] = fexp2(st[r]);
                } else {
                    #pragma unroll
                    for (int r = 0; r < 16; ++r) {
                        const int ki = kh + (r & 3) + 8 * (r >> 2) + 4 * hi;
                        const bool ok = (ki <= q) && (ki + kW >= q);
                        const float e = fexp2(st[r]);
                        p[r] = ok ? e : 0.f;
                    }
                }

                // P^T -> bf16 B-frags (verified cvt_pk + permlane order)
                unsigned int wrd[8];
                #pragma unroll
                for (int j = 0; j < 8; ++j)
                    asm("v_cvt_pk_bf16_f32 %0, %1, %2" : "=v"(wrd[j]) : "v"(p[2 * j]), "v"(p[2 * j + 1]));
                asm("v_permlane32_swap_b32 %0, %1" : "+v"(wrd[0]), "+v"(wrd[2]));
                asm("v_permlane32_swap_b32 %0, %1" : "+v"(wrd[1]), "+v"(wrd[3]));
                asm("v_permlane32_swap_b32 %0, %1" : "+v"(wrd[4]), "+v"(wrd[6]));
                asm("v_permlane32_swap_b32 %0, %1" : "+v"(wrd[5]), "+v"(wrd[7]));
                union U { unsigned int u[4]; bf16x8 v; };
                U u0, u1;
                u0.u[0] = wrd[0]; u0.u[1] = wrd[1]; u0.u[2] = wrd[2]; u0.u[3] = wrd[3];
                u1.u[0] = wrd[4]; u1.u[1] = wrd[5]; u1.u[2] = wrd[6]; u1.u[3] = wrd[7];

                __builtin_amdgcn_s_setprio(1);
                acc[0] = __builtin_amdgcn_mfma_f32_32x32x16_bf16(vf[0], u0.v, acc[0], 0, 0, 0);
                acc[1] = __builtin_amdgcn_mfma_f32_32x32x16_bf16(vf[2], u0.v, acc[1], 0, 0, 0);
                lsum   = __builtin_amdgcn_mfma_f32_32x32x16_bf16(ones,  u0.v, lsum,   0, 0, 0);
                acc[0] = __builtin_amdgcn_mfma_f32_32x32x16_bf16(vf[1], u1.v, acc[0], 0, 0, 0);
                acc[1] = __builtin_amdgcn_mfma_f32_32x32x16_bf16(vf[3], u1.v, acc[1], 0, 0, 0);
                lsum   = __builtin_amdgcn_mfma_f32_32x32x16_bf16(ones,  u1.v, lsum,   0, 0, 0);
                __builtin_amdgcn_s_setprio(0);
            }
        }

        asm volatile("" ::: "memory");
        __builtin_amdgcn_s_barrier();                   // buf fully read before rewrite
        asm volatile("" ::: "memory");
    }

    // ---- epilogue: denominator from lsum (all regs = row sum), store ----
    const float rl = 1.f / lsum[0];
    float* op = Og + hb + (size_t)q * kD;
    #pragma unroll
    for (int g = 0; g < 4; ++g) {
        float4_t o0, o1;
        #pragma unroll
        for (int j = 0; j < 4; ++j) {
            o0[j] = acc[0][g * 4 + j] * rl;
            o1[j] = acc[1][g * 4 + j] * rl;
        }
        *(float4_t*)(op + g * 8 + hi * 4)      = o0;
        *(float4_t*)(op + 32 + g * 8 + hi * 4) = o1;
    }
}
} // namespace

extern "C" void kernel_launch(void* const* d_in, const int* in_sizes, int n_in,
                              void* d_out, int out_size, void* d_ws, size_t ws_size,
                              hipStream_t stream) {
    (void)in_sizes; (void)n_in; (void)out_size; (void)ws_size;
    const float* Q = (const float*)d_in[0];
    const float* K = (const float*)d_in[1];
    const float* V = (const float*)d_in[2];
    float* O = (float*)d_out;
    unsigned short* Kb = (unsigned short*)d_ws;
    unsigned short* Vt = Kb + (size_t)kH * kS * kD;

    prep_kv<<<dim3(kS / 64, kH), dim3(256), 0, stream>>>(K, V, Kb, Vt);
    swa_main<<<dim3(1024), dim3(256), 0, stream>>>(Q, Kb, Vt, O);
}

// Round 13
// 78.687 us; speedup vs baseline: 2.5314x; 1.0075x over previous
//
#include <hip/hip_runtime.h>
#include <stdint.h>

namespace {
constexpr int kH = 16;
constexpr int kS = 8192;
constexpr int kD = 64;
constexpr int kW = 1024;

typedef __attribute__((ext_vector_type(4)))  float float4_t;
typedef __attribute__((ext_vector_type(16))) float f32x16;
typedef __attribute__((ext_vector_type(8)))  short bf16x8;
typedef __attribute__((ext_vector_type(8)))  short short8_t;

__device__ __forceinline__ unsigned short f2bf(float f) {
    union { float fv; uint32_t u; } c; c.fv = f;
    return (unsigned short)((c.u + 0x7fffu + ((c.u >> 16) & 1u)) >> 16);
}

__device__ __forceinline__ float fexp2(float x) {
#if __has_builtin(__builtin_amdgcn_exp2f)
    return __builtin_amdgcn_exp2f(x);
#else
    return exp2f(x);
#endif
}

__device__ __forceinline__ void gload16(const void* g, char* l) {
    __builtin_amdgcn_global_load_lds(
        (const __attribute__((address_space(1))) void*)g,
        (__attribute__((address_space(3))) void*)l, 16, 0, 0);
}

// ---- fused prepass: K fp32->bf16 + V transpose (64 seq rows per block) ----
__global__ __launch_bounds__(256)
void prep_kv(const float* __restrict__ K, const float* __restrict__ V,
             unsigned short* __restrict__ Kb, unsigned short* __restrict__ Vt) {
    __shared__ float tile[64][65];
    const int h  = blockIdx.y;
    const int s0 = blockIdx.x * 64;
    const int tid = threadIdx.x;
    const size_t hb = (size_t)h * kS * kD;

    // K convert: 64x64 elems, 16 per thread
    {
        const size_t base = hb + (size_t)s0 * kD + (size_t)tid * 16;
        float4_t a = *(const float4_t*)(K + base);
        float4_t b = *(const float4_t*)(K + base + 4);
        float4_t c = *(const float4_t*)(K + base + 8);
        float4_t d = *(const float4_t*)(K + base + 12);
        short8_t o0, o1;
        #pragma unroll
        for (int j = 0; j < 4; ++j) {
            o0[j] = (short)f2bf(a[j]); o0[j + 4] = (short)f2bf(b[j]);
            o1[j] = (short)f2bf(c[j]); o1[j + 4] = (short)f2bf(d[j]);
        }
        *(short8_t*)(Kb + base)     = o0;
        *(short8_t*)(Kb + base + 8) = o1;
    }

    // V transpose -> Vt [D][S]
    #pragma unroll
    for (int it = 0; it < 4; ++it) {
        const int n = tid + it * 256;
        const int s = n >> 4, d0 = (n & 15) * 4;
        float4_t v = *(const float4_t*)(V + hb + (size_t)(s0 + s) * kD + d0);
        tile[s][d0 + 0] = v[0]; tile[s][d0 + 1] = v[1];
        tile[s][d0 + 2] = v[2]; tile[s][d0 + 3] = v[3];
    }
    __syncthreads();
    #pragma unroll
    for (int it = 0; it < 2; ++it) {
        const int n = tid + it * 256;
        const int d = n >> 3, sc = (n & 7) * 8;
        short8_t o;
        #pragma unroll
        for (int j = 0; j < 8; ++j) o[j] = (short)f2bf(tile[sc + j][d]);
        *(short8_t*)(Vt + (size_t)h * kD * kS + (size_t)d * kS + s0 + sc) = o;
    }
}

// ---- main: 64 q/wave (2 subtiles share kf/vf), R6 staging skeleton ----
__global__ __launch_bounds__(256, 2)
void swa_main(const float* __restrict__ Qg, const unsigned short* __restrict__ Kb,
              const unsigned short* __restrict__ Vt, float* __restrict__ Og) {
    // per buffer: [0,8K) K tile [64 keys][128B], [8K,16K) V^T tile [64 d][128B]
    __shared__ __align__(16) char lds[2][16384];

    const int lid  = blockIdx.x;                      // 0..511
    const int swz  = (lid & 7) * 64 + (lid >> 3);     // XCD-chunked, bijective
    const int h    = swz >> 5;
    const int qblk = swz & 31;

    const int tid  = threadIdx.x;
    const int wv   = tid >> 6;
    const int lane = tid & 63;
    const int lq   = lane & 31;
    const int hi   = lane >> 5;

    const int q0b = qblk * 256;          // block's first query
    const int qs  = q0b + wv * 64;       // wave's first query (64 q/wave)
    const size_t hb  = (size_t)h * kS * kD;
    const size_t hbv = (size_t)h * kD * kS;

    // ---- Q B-fragments for 2 subtiles; scale folded with log2(e) ----
    constexpr float qscale = 0.125f * 1.44269504f;
    bf16x8 qf[2][4];
    #pragma unroll
    for (int s = 0; s < 2; ++s) {
        const float* qp = Qg + hb + (size_t)(qs + 32 * s + lq) * kD + hi * 8;
        #pragma unroll
        for (int c = 0; c < 4; ++c) {
            float4_t a = *(const float4_t*)(qp + c * 16);
            float4_t b = *(const float4_t*)(qp + c * 16 + 4);
            bf16x8 f;
            #pragma unroll
            for (int j = 0; j < 4; ++j) {
                f[j]     = (short)f2bf(a[j] * qscale);
                f[j + 4] = (short)f2bf(b[j] * qscale);
            }
            qf[s][c] = f;
        }
    }

    f32x16 acc[2][2];                    // [subtile][d-half]
    #pragma unroll
    for (int s = 0; s < 2; ++s)
        #pragma unroll
        for (int hf = 0; hf < 2; ++hf)
            #pragma unroll
            for (int r = 0; r < 16; ++r) acc[s][hf][r] = 0.f;
    float l4[2][4] = {{0.f,0.f,0.f,0.f},{0.f,0.f,0.f,0.f}};

    const int kstart = (q0b >= kW) ? q0b - kW : 0;
    const int nt     = (q0b + 256 - kstart) >> 6;

    // staging: dest chunk n = tid + i*256 (linear); src chunk c = n ^ ((n>>3)&7)
    int srcK[2], srcV[2];
    #pragma unroll
    for (int i = 0; i < 2; ++i) {
        const int n = tid + i * 256;
        const int c = n ^ ((n >> 3) & 7);
        srcK[i] = (c >> 3) * 64 + (c & 7) * 8;
        srcV[i] = (c >> 3) * kS + (c & 7) * 8;
    }
    const unsigned short* KbH = Kb + hb;
    const unsigned short* VtH = Vt + hbv;

    auto stage = [&](int buf, int kb) {
        const unsigned short* Kt = KbH + (size_t)kb * 64;
        const unsigned short* Vq = VtH + kb;
        #pragma unroll
        for (int i = 0; i < 2; ++i) {
            const int db = i * 4096 + wv * 1024;
            gload16(Kt + srcK[i], &lds[buf][db]);
            gload16(Vq + srcV[i], &lds[buf][8192 + db]);
        }
    };

    stage(0, kstart);
    for (int t = 0; t < nt; ++t) {
        const int kb  = kstart + t * 64;
        const int kbn = (t + 1 < nt) ? kb + 64 : kb;
        stage((t + 1) & 1, kbn);                         // prefetch next tile
        asm volatile("s_waitcnt vmcnt(4)" ::: "memory"); // tile t staged; 4 newest in flight
        __builtin_amdgcn_s_barrier();
        asm volatile("" ::: "memory");

        const char* Kl = lds[t & 1];
        const char* Vl = lds[t & 1] + 8192;

        #pragma unroll
        for (int half = 0; half < 2; ++half) {
            const int kh = kb + half * 32;
            const bool a0 = (kh <= qs)      && (kh >= qs - kW);
            const bool a1 = (kh <= qs + 32) && (kh >= qs + 32 - kW);
            if (a0 || a1) {                              // wave-uniform
                // K A-frags (shared by both subtiles)
                const int krow = half * 32 + lq;
                const int ksw  = (lq & 7) << 4;          // krow&7 == lq&7
                bf16x8 kf[4];
                #pragma unroll
                for (int c = 0; c < 4; ++c)
                    kf[c] = *(const bf16x8*)(Kl + ((krow * 128 + c * 32 + hi * 16) ^ ksw));

                f32x16 st0, st1;
                #pragma unroll
                for (int r = 0; r < 16; ++r) { st0[r] = 0.f; st1[r] = 0.f; }
                __builtin_amdgcn_s_setprio(1);
                if (a0) {
                    #pragma unroll
                    for (int c = 0; c < 4; ++c)
                        st0 = __builtin_amdgcn_mfma_f32_32x32x16_bf16(kf[c], qf[0][c], st0, 0, 0, 0);
                }
                if (a1) {
                    #pragma unroll
                    for (int c = 0; c < 4; ++c)
                        st1 = __builtin_amdgcn_mfma_f32_32x32x16_bf16(kf[c], qf[1][c], st1, 0, 0, 0);
                }
                __builtin_amdgcn_s_setprio(0);

                // V A-frags (shared by both subtiles)
                bf16x8 vf[4];
                #pragma unroll
                for (int dh = 0; dh < 2; ++dh)
                    #pragma unroll
                    for (int kc = 0; kc < 2; ++kc)
                        vf[dh * 2 + kc] = *(const bf16x8*)(
                            Vl + (((dh * 32 + lq) * 128 + half * 64 + kc * 32 + hi * 16) ^ ksw));

                #pragma unroll
                for (int s = 0; s < 2; ++s) {
                    if (s == 0 ? !a0 : !a1) continue;
                    const int qss = qs + 32 * s;
                    const f32x16& st = (s == 0) ? st0 : st1;

                    // max-free softmax numerators (exp2 domain)
                    float p[16];
                    const bool interior = (kh <= qss - 32) && (kh >= qss - 992);
                    if (interior) {
                        #pragma unroll
                        for (int r = 0; r < 16; ++r) p[r] = fexp2(st[r]);
                    } else {
                        #pragma unroll
                        for (int r = 0; r < 16; ++r) {
                            const int ki = kh + (r & 3) + 8 * (r >> 2) + 4 * hi;
                            const int q  = qss + lq;
                            const bool ok = (ki <= q) && (ki + kW >= q);
                            const float e = fexp2(st[r]);
                            p[r] = ok ? e : 0.f;
                        }
                    }
                    #pragma unroll
                    for (int r = 0; r < 16; ++r) l4[s][r & 3] += p[r];

                    // P^T -> bf16 B-frags (verified cvt_pk + permlane order)
                    unsigned int wrd[8];
                    #pragma unroll
                    for (int j = 0; j < 8; ++j)
                        asm("v_cvt_pk_bf16_f32 %0, %1, %2" : "=v"(wrd[j]) : "v"(p[2 * j]), "v"(p[2 * j + 1]));
                    asm("v_permlane32_swap_b32 %0, %1" : "+v"(wrd[0]), "+v"(wrd[2]));
                    asm("v_permlane32_swap_b32 %0, %1" : "+v"(wrd[1]), "+v"(wrd[3]));
                    asm("v_permlane32_swap_b32 %0, %1" : "+v"(wrd[4]), "+v"(wrd[6]));
                    asm("v_permlane32_swap_b32 %0, %1" : "+v"(wrd[5]), "+v"(wrd[7]));
                    union U { unsigned int u[4]; bf16x8 v; };
                    U u0, u1;
                    u0.u[0] = wrd[0]; u0.u[1] = wrd[1]; u0.u[2] = wrd[2]; u0.u[3] = wrd[3];
                    u1.u[0] = wrd[4]; u1.u[1] = wrd[5]; u1.u[2] = wrd[6]; u1.u[3] = wrd[7];

                    __builtin_amdgcn_s_setprio(1);
                    acc[s][0] = __builtin_amdgcn_mfma_f32_32x32x16_bf16(vf[0], u0.v, acc[s][0], 0, 0, 0);
                    acc[s][1] = __builtin_amdgcn_mfma_f32_32x32x16_bf16(vf[2], u0.v, acc[s][1], 0, 0, 0);
                    acc[s][0] = __builtin_amdgcn_mfma_f32_32x32x16_bf16(vf[1], u1.v, acc[s][0], 0, 0, 0);
                    acc[s][1] = __builtin_amdgcn_mfma_f32_32x32x16_bf16(vf[3], u1.v, acc[s][1], 0, 0, 0);
                    __builtin_amdgcn_s_setprio(0);
                }
            }
        }

        asm volatile("" ::: "memory");
        __builtin_amdgcn_s_barrier();                   // buf fully read before rewrite
        asm volatile("" ::: "memory");
    }

    // ---- epilogue: per-subtile denominator + store ----
    #pragma unroll
    for (int s = 0; s < 2; ++s) {
        float l = (l4[s][0] + l4[s][1]) + (l4[s][2] + l4[s][3]);
        l += __shfl_xor(l, 32);
        const float rl = 1.f / l;
        float* op = Og + hb + (size_t)(qs + 32 * s + lq) * kD;
        #pragma unroll
        for (int g = 0; g < 4; ++g) {
            float4_t o0, o1;
            #pragma unroll
            for (int j = 0; j < 4; ++j) {
                o0[j] = acc[s][0][g * 4 + j] * rl;
                o1[j] = acc[s][1][g * 4 + j] * rl;
            }
            *(float4_t*)(op + g * 8 + hi * 4)      = o0;
            *(float4_t*)(op + 32 + g * 8 + hi * 4) = o1;
        }
    }
}
} // namespace

extern "C" void kernel_launch(void* const* d_in, const int* in_sizes, int n_in,
                              void* d_out, int out_size, void* d_ws, size_t ws_size,
                              hipStream_t stream) {
    (void)in_sizes; (void)n_in; (void)out_size; (void)ws_size;
    const float* Q = (const float*)d_in[0];
    const float* K = (const float*)d_in[1];
    const float* V = (const float*)d_in[2];
    float* O = (float*)d_out;
    unsigned short* Kb = (unsigned short*)d_ws;
    unsigned short* Vt = Kb + (size_t)kH * kS * kD;

    prep_kv<<<dim3(kS / 64, kH), dim3(256), 0, stream>>>(K, V, Kb, Vt);
    swa_main<<<dim3(512), dim3(256), 0, stream>>>(Q, Kb, Vt, O);
}

// Round 14
// 70.758 us; speedup vs baseline: 2.8150x; 1.1121x over previous
//
#include <hip/hip_runtime.h>
#include <stdint.h>

namespace {
constexpr int kH = 16;
constexpr int kS = 8192;
constexpr int kD = 64;
constexpr int kW = 1024;

typedef __attribute__((ext_vector_type(4)))  float float4_t;
typedef __attribute__((ext_vector_type(16))) float f32x16;
typedef __attribute__((ext_vector_type(8)))  short bf16x8;
typedef __attribute__((ext_vector_type(8)))  short short8_t;

__device__ __forceinline__ unsigned short f2bf(float f) {
    union { float fv; uint32_t u; } c; c.fv = f;
    return (unsigned short)((c.u + 0x7fffu + ((c.u >> 16) & 1u)) >> 16);
}

__device__ __forceinline__ float fexp2(float x) {
#if __has_builtin(__builtin_amdgcn_exp2f)
    return __builtin_amdgcn_exp2f(x);
#else
    return exp2f(x);
#endif
}

__device__ __forceinline__ void gload16(const void* g, char* l) {
    __builtin_amdgcn_global_load_lds(
        (const __attribute__((address_space(1))) void*)g,
        (__attribute__((address_space(3))) void*)l, 16, 0, 0);
}

// P^T f32[16] -> two bf16x8 B-fragments (verified cvt_pk + permlane order)
#define P_TO_FRAGS(P, U0, U1)                                                            \
    {                                                                                    \
        unsigned int wrd[8];                                                             \
        _Pragma("unroll")                                                                \
        for (int j = 0; j < 8; ++j)                                                      \
            asm("v_cvt_pk_bf16_f32 %0, %1, %2" : "=v"(wrd[j]) : "v"(P[2*j]), "v"(P[2*j+1])); \
        asm("v_permlane32_swap_b32 %0, %1" : "+v"(wrd[0]), "+v"(wrd[2]));                \
        asm("v_permlane32_swap_b32 %0, %1" : "+v"(wrd[1]), "+v"(wrd[3]));                \
        asm("v_permlane32_swap_b32 %0, %1" : "+v"(wrd[4]), "+v"(wrd[6]));                \
        asm("v_permlane32_swap_b32 %0, %1" : "+v"(wrd[5]), "+v"(wrd[7]));                \
        U0.u[0] = wrd[0]; U0.u[1] = wrd[1]; U0.u[2] = wrd[2]; U0.u[3] = wrd[3];          \
        U1.u[0] = wrd[4]; U1.u[1] = wrd[5]; U1.u[2] = wrd[6]; U1.u[3] = wrd[7];          \
    }

// ---- fused prepass: K fp32->bf16 + V transpose (64 seq rows per block) ----
__global__ __launch_bounds__(256)
void prep_kv(const float* __restrict__ K, const float* __restrict__ V,
             unsigned short* __restrict__ Kb, unsigned short* __restrict__ Vt) {
    __shared__ float tile[64][65];
    const int h  = blockIdx.y;
    const int s0 = blockIdx.x * 64;
    const int tid = threadIdx.x;
    const size_t hb = (size_t)h * kS * kD;

    {
        const size_t base = hb + (size_t)s0 * kD + (size_t)tid * 16;
        float4_t a = *(const float4_t*)(K + base);
        float4_t b = *(const float4_t*)(K + base + 4);
        float4_t c = *(const float4_t*)(K + base + 8);
        float4_t d = *(const float4_t*)(K + base + 12);
        short8_t o0, o1;
        #pragma unroll
        for (int j = 0; j < 4; ++j) {
            o0[j] = (short)f2bf(a[j]); o0[j + 4] = (short)f2bf(b[j]);
            o1[j] = (short)f2bf(c[j]); o1[j + 4] = (short)f2bf(d[j]);
        }
        *(short8_t*)(Kb + base)     = o0;
        *(short8_t*)(Kb + base + 8) = o1;
    }

    #pragma unroll
    for (int it = 0; it < 4; ++it) {
        const int n = tid + it * 256;
        const int s = n >> 4, d0 = (n & 15) * 4;
        float4_t v = *(const float4_t*)(V + hb + (size_t)(s0 + s) * kD + d0);
        tile[s][d0 + 0] = v[0]; tile[s][d0 + 1] = v[1];
        tile[s][d0 + 2] = v[2]; tile[s][d0 + 3] = v[3];
    }
    __syncthreads();
    #pragma unroll
    for (int it = 0; it < 2; ++it) {
        const int n = tid + it * 256;
        const int d = n >> 3, sc = (n & 7) * 8;
        short8_t o;
        #pragma unroll
        for (int j = 0; j < 8; ++j) o[j] = (short)f2bf(tile[sc + j][d]);
        *(short8_t*)(Vt + (size_t)h * kD * kS + (size_t)d * kS + s0 + sc) = o;
    }
}

// ---- main: R6 skeleton + straight-line fused fast path for interior tiles ----
__global__ __launch_bounds__(256, 4)
void swa_main(const float* __restrict__ Qg, const unsigned short* __restrict__ Kb,
              const unsigned short* __restrict__ Vt, float* __restrict__ Og) {
    __shared__ __align__(16) char lds[2][16384];

    const int lid  = blockIdx.x;                      // 0..1023
    const int swz  = (lid & 7) * 128 + (lid >> 3);    // XCD-chunked, bijective
    const int h    = swz >> 6;
    const int qblk = swz & 63;

    const int tid  = threadIdx.x;
    const int wv   = tid >> 6;
    const int lane = tid & 63;
    const int lq   = lane & 31;
    const int hi   = lane >> 5;

    const int q0b = qblk * 128;
    const int qs  = q0b + wv * 32;
    const int q   = qs + lq;
    const size_t hb  = (size_t)h * kS * kD;
    const size_t hbv = (size_t)h * kD * kS;

    constexpr float qscale = 0.125f * 1.44269504f;
    bf16x8 qf[4];
    {
        const float* qp = Qg + hb + (size_t)q * kD + hi * 8;
        #pragma unroll
        for (int c = 0; c < 4; ++c) {
            float4_t a = *(const float4_t*)(qp + c * 16);
            float4_t b = *(const float4_t*)(qp + c * 16 + 4);
            bf16x8 f;
            #pragma unroll
            for (int j = 0; j < 4; ++j) {
                f[j]     = (short)f2bf(a[j] * qscale);
                f[j + 4] = (short)f2bf(b[j] * qscale);
            }
            qf[c] = f;
        }
    }

    f32x16 acc[2];
    #pragma unroll
    for (int r = 0; r < 16; ++r) { acc[0][r] = 0.f; acc[1][r] = 0.f; }
    float l4[4] = {0.f, 0.f, 0.f, 0.f};

    const int kstart = (q0b >= kW) ? q0b - kW : 0;
    const int nt     = (q0b + 128 - kstart) >> 6;

    int srcK[2], srcV[2];
    #pragma unroll
    for (int i = 0; i < 2; ++i) {
        const int n = tid + i * 256;
        const int c = n ^ ((n >> 3) & 7);
        srcK[i] = (c >> 3) * 64 + (c & 7) * 8;
        srcV[i] = (c >> 3) * kS + (c & 7) * 8;
    }
    const unsigned short* KbH = Kb + hb;
    const unsigned short* VtH = Vt + hbv;

    auto stage = [&](int buf, int kb) {
        const unsigned short* Kt = KbH + (size_t)kb * 64;
        const unsigned short* Vq = VtH + kb;
        #pragma unroll
        for (int i = 0; i < 2; ++i) {
            const int db = i * 4096 + wv * 1024;
            gload16(Kt + srcK[i], &lds[buf][db]);
            gload16(Vq + srcV[i], &lds[buf][8192 + db]);
        }
    };

    union U { unsigned int u[4]; bf16x8 v; };

    stage(0, kstart);
    for (int t = 0; t < nt; ++t) {
        const int kb  = kstart + t * 64;
        const int kbn = (t + 1 < nt) ? kb + 64 : kb;
        stage((t + 1) & 1, kbn);
        asm volatile("s_waitcnt vmcnt(4)" ::: "memory");
        __builtin_amdgcn_s_barrier();
        asm volatile("" ::: "memory");

        const char* Kl = lds[t & 1];
        const char* Vl = lds[t & 1] + 8192;
        const int ksw = (lq & 7) << 4;

        const bool fast = (kb >= qs - 992) && (kb + 32 <= qs - 32);  // both halves interior

        if (fast) {
            // ---- straight-line fused both-halves path (no masks, no branches) ----
            bf16x8 kf0[4], kf1[4], vf0[4], vf1[4];
            #pragma unroll
            for (int c = 0; c < 4; ++c) {
                kf0[c] = *(const bf16x8*)(Kl + ((lq * 128        + c * 32 + hi * 16) ^ ksw));
                kf1[c] = *(const bf16x8*)(Kl + (((32 + lq) * 128 + c * 32 + hi * 16) ^ ksw));
            }
            #pragma unroll
            for (int dh = 0; dh < 2; ++dh)
                #pragma unroll
                for (int kc = 0; kc < 2; ++kc) {
                    vf0[dh * 2 + kc] = *(const bf16x8*)(
                        Vl + (((dh * 32 + lq) * 128 + kc * 32 + hi * 16) ^ ksw));
                    vf1[dh * 2 + kc] = *(const bf16x8*)(
                        Vl + (((dh * 32 + lq) * 128 + 64 + kc * 32 + hi * 16) ^ ksw));
                }

            f32x16 st0, st1;
            #pragma unroll
            for (int r = 0; r < 16; ++r) { st0[r] = 0.f; st1[r] = 0.f; }
            #pragma unroll
            for (int c = 0; c < 4; ++c) {
                st0 = __builtin_amdgcn_mfma_f32_32x32x16_bf16(kf0[c], qf[c], st0, 0, 0, 0);
                st1 = __builtin_amdgcn_mfma_f32_32x32x16_bf16(kf1[c], qf[c], st1, 0, 0, 0);
            }

            float p0[16], p1[16];
            #pragma unroll
            for (int r = 0; r < 16; ++r) { p0[r] = fexp2(st0[r]); p1[r] = fexp2(st1[r]); }
            #pragma unroll
            for (int r = 0; r < 16; ++r) l4[r & 3] += p0[r] + p1[r];

            U a00, a01, a10, a11;
            P_TO_FRAGS(p0, a00, a01);
            P_TO_FRAGS(p1, a10, a11);

            acc[0] = __builtin_amdgcn_mfma_f32_32x32x16_bf16(vf0[0], a00.v, acc[0], 0, 0, 0);
            acc[1] = __builtin_amdgcn_mfma_f32_32x32x16_bf16(vf0[2], a00.v, acc[1], 0, 0, 0);
            acc[0] = __builtin_amdgcn_mfma_f32_32x32x16_bf16(vf0[1], a01.v, acc[0], 0, 0, 0);
            acc[1] = __builtin_amdgcn_mfma_f32_32x32x16_bf16(vf0[3], a01.v, acc[1], 0, 0, 0);
            acc[0] = __builtin_amdgcn_mfma_f32_32x32x16_bf16(vf1[0], a10.v, acc[0], 0, 0, 0);
            acc[1] = __builtin_amdgcn_mfma_f32_32x32x16_bf16(vf1[2], a10.v, acc[1], 0, 0, 0);
            acc[0] = __builtin_amdgcn_mfma_f32_32x32x16_bf16(vf1[1], a11.v, acc[0], 0, 0, 0);
            acc[1] = __builtin_amdgcn_mfma_f32_32x32x16_bf16(vf1[3], a11.v, acc[1], 0, 0, 0);
        } else {
            // ---- edge path: per-half guarded + masked (R6-verified) ----
            #pragma unroll
            for (int half = 0; half < 2; ++half) {
                const int kh = kb + half * 32;
                if (kh <= qs && kh >= qs - kW) {
                    const int krow = half * 32 + lq;
                    bf16x8 kf[4];
                    #pragma unroll
                    for (int c = 0; c < 4; ++c)
                        kf[c] = *(const bf16x8*)(Kl + ((krow * 128 + c * 32 + hi * 16) ^ ksw));

                    f32x16 st;
                    #pragma unroll
                    for (int r = 0; r < 16; ++r) st[r] = 0.f;
                    __builtin_amdgcn_s_setprio(1);
                    #pragma unroll
                    for (int c = 0; c < 4; ++c)
                        st = __builtin_amdgcn_mfma_f32_32x32x16_bf16(kf[c], qf[c], st, 0, 0, 0);
                    __builtin_amdgcn_s_setprio(0);

                    bf16x8 vf[4];
                    #pragma unroll
                    for (int dh = 0; dh < 2; ++dh)
                        #pragma unroll
                        for (int kc = 0; kc < 2; ++kc)
                            vf[dh * 2 + kc] = *(const bf16x8*)(
                                Vl + (((dh * 32 + lq) * 128 + half * 64 + kc * 32 + hi * 16) ^ ksw));

                    float p[16];
                    #pragma unroll
                    for (int r = 0; r < 16; ++r) {
                        const int ki = kh + (r & 3) + 8 * (r >> 2) + 4 * hi;
                        const bool ok = (ki <= q) && (ki + kW >= q);
                        const float e = fexp2(st[r]);
                        p[r] = ok ? e : 0.f;
                    }
                    #pragma unroll
                    for (int r = 0; r < 16; ++r) l4[r & 3] += p[r];

                    U u0, u1;
                    P_TO_FRAGS(p, u0, u1);

                    __builtin_amdgcn_s_setprio(1);
                    acc[0] = __builtin_amdgcn_mfma_f32_32x32x16_bf16(vf[0], u0.v, acc[0], 0, 0, 0);
                    acc[1] = __builtin_amdgcn_mfma_f32_32x32x16_bf16(vf[2], u0.v, acc[1], 0, 0, 0);
                    acc[0] = __builtin_amdgcn_mfma_f32_32x32x16_bf16(vf[1], u1.v, acc[0], 0, 0, 0);
                    acc[1] = __builtin_amdgcn_mfma_f32_32x32x16_bf16(vf[3], u1.v, acc[1], 0, 0, 0);
                    __builtin_amdgcn_s_setprio(0);
                }
            }
        }

        asm volatile("" ::: "memory");
        __builtin_amdgcn_s_barrier();
        asm volatile("" ::: "memory");
    }

    // ---- epilogue ----
    float l = (l4[0] + l4[1]) + (l4[2] + l4[3]);
    l += __shfl_xor(l, 32);
    const float rl = 1.f / l;
    float* op = Og + hb + (size_t)q * kD;
    #pragma unroll
    for (int g = 0; g < 4; ++g) {
        float4_t o0, o1;
        #pragma unroll
        for (int j = 0; j < 4; ++j) {
            o0[j] = acc[0][g * 4 + j] * rl;
            o1[j] = acc[1][g * 4 + j] * rl;
        }
        *(float4_t*)(op + g * 8 + hi * 4)      = o0;
        *(float4_t*)(op + 32 + g * 8 + hi * 4) = o1;
    }
}
} // namespace

extern "C" void kernel_launch(void* const* d_in, const int* in_sizes, int n_in,
                              void* d_out, int out_size, void* d_ws, size_t ws_size,
                              hipStream_t stream) {
    (void)in_sizes; (void)n_in; (void)out_size; (void)ws_size;
    const float* Q = (const float*)d_in[0];
    const float* K = (const float*)d_in[1];
    const float* V = (const float*)d_in[2];
    float* O = (float*)d_out;
    unsigned short* Kb = (unsigned short*)d_ws;
    unsigned short* Vt = Kb + (size_t)kH * kS * kD;

    prep_kv<<<dim3(kS / 64, kH), dim3(256), 0, stream>>>(K, V, Kb, Vt);
    swa_main<<<dim3(1024), dim3(256), 0, stream>>>(Q, Kb, Vt, O);
}